// Round 10
// baseline (120.021 us; speedup 1.0000x reference)
//
#include <hip/hip_runtime.h>
#include <hip/hip_bf16.h>
#include <hip/hip_fp16.h>

#define NB 4
#define NS 2048
#define NE 128
#define NH 16
#define ND 8

#define VT_BLK 144                 // shorts per 16-t block: 9 rows x 16 slots
#define VT_BH (128 * VT_BLK)       // shorts per (b,h): 128 blocks = 18432

typedef __attribute__((ext_vector_type(8))) _Float16 half8;
typedef __attribute__((ext_vector_type(4))) float f32x4;
typedef __attribute__((ext_vector_type(16))) float f32x16;

__device__ __forceinline__ unsigned int pkrtz(float a, float b) {
    typedef __fp16 fp16v2 __attribute__((ext_vector_type(2)));
    union { fp16v2 h; unsigned int u; } v;
    v.h = __builtin_amdgcn_cvt_pkrtz(a, b);
    return v.u;
}
__device__ __forceinline__ half8 mk_half8(unsigned u0, unsigned u1,
                                          unsigned u2, unsigned u3) {
    union { half8 h; unsigned u[4]; } v;
    v.u[0] = u0; v.u[1] = u1; v.u[2] = u2; v.u[3] = u3;
    return v.h;
}

// cumprod-of-cos row: p[d] = prod_{i<=d} cos(x[i] + th[i])
__device__ __forceinline__ void qrow(const float* __restrict__ xp,
                                     const float* th, float* p) {
    float4 a = *(const float4*)xp, c = *(const float4*)(xp + 4);
    float t = 1.f;
    t *= cosf(a.x + th[0]); p[0] = t;
    t *= cosf(a.y + th[1]); p[1] = t;
    t *= cosf(a.z + th[2]); p[2] = t;
    t *= cosf(a.w + th[3]); p[3] = t;
    t *= cosf(c.x + th[4]); p[4] = t;
    t *= cosf(c.y + th[5]); p[5] = t;
    t *= cosf(c.z + th[6]); p[6] = t;
    t *= cosf(c.w + th[7]); p[7] = t;
}

// qgen (unchanged from R14): q once per (b,h,s).
//   qg  [b][h][s][d] f16 pre-scaled by SC
//   vtg [b][h][blk=s/16][d=0..8][slot] f16, pi2-ordered, mask folded,
//       d=8 = ones/mask row. Block 0 also converts w -> wf16.
__global__ __launch_bounds__(256) void qgen_kernel(
        const float* __restrict__ x,
        const float* __restrict__ theta,
        const int* __restrict__ mask,
        const float* __restrict__ w,
        unsigned short* __restrict__ qg,
        unsigned short* __restrict__ vtg,
        unsigned short* __restrict__ wf16) {
    const int gid = blockIdx.x * 256 + threadIdx.x;   // 0..65535
    const int bh = gid >> 10;           // (b,h), 0..63
    const int b = bh >> 4, h = bh & (NH - 1);
    const int j = gid & 1023;           // pair within (b,h)
    const int s0 = 2 * j;
    const float SC = 0.71421629f;       // sqrt(log2(e)/sqrt(8))

    if (blockIdx.x == 0) {              // one-time w -> f16 (row-major [n][k])
        for (int i = threadIdx.x; i < 2048; i += 256) {
            const float* wp = w + i * 8;
            float4 a = *(const float4*)wp, c = *(const float4*)(wp + 4);
            uint4 pk;
            pk.x = pkrtz(a.x, a.y); pk.y = pkrtz(a.z, a.w);
            pk.z = pkrtz(c.x, c.y); pk.w = pkrtz(c.z, c.w);
            *(uint4*)&wf16[i * 8] = pk;
        }
    }

    float th[ND];
#pragma unroll
    for (int d = 0; d < ND; d++) th[d] = theta[d];

    float p0[ND], p1[ND];
    qrow(x + ((size_t)(b * NS + s0) * NE + h * ND), th, p0);
    qrow(x + ((size_t)(b * NS + s0 + 1) * NE + h * ND), th, p1);
    const float mz0 = mask[b * NS + s0] ? 1.f : 0.f;
    const float mz1 = mask[b * NS + s0 + 1] ? 1.f : 0.f;

    uint4 qa, qb;
    qa.x = pkrtz(p0[0] * SC, p0[1] * SC);
    qa.y = pkrtz(p0[2] * SC, p0[3] * SC);
    qa.z = pkrtz(p0[4] * SC, p0[5] * SC);
    qa.w = pkrtz(p0[6] * SC, p0[7] * SC);
    qb.x = pkrtz(p1[0] * SC, p1[1] * SC);
    qb.y = pkrtz(p1[2] * SC, p1[3] * SC);
    qb.z = pkrtz(p1[4] * SC, p1[5] * SC);
    qb.w = pkrtz(p1[6] * SC, p1[7] * SC);
    *(uint4*)&qg[((size_t)bh * NS + s0) * ND] = qa;
    *(uint4*)&qg[((size_t)bh * NS + s0 + 1) * ND] = qb;

    // pi2 slot for s0 (even -> slot even; s0+1 lands in slot+1)
    const int blk = s0 >> 4, u = s0 & 15;
    const int k2 = (u & 3) | (((u >> 3) & 1) << 2) | (((u >> 2) & 1) << 3);
    unsigned short* vb = vtg + (size_t)bh * VT_BH + blk * VT_BLK + k2;
#pragma unroll
    for (int d = 0; d < ND; d++)
        *(unsigned int*)&vb[d * 16] = pkrtz(p0[d] * mz0, p1[d] * mz1);
    *(unsigned int*)&vb[8 * 16] = pkrtz(mz0, mz1);   // ones/mask row
}

// R15 attn: R14's math (verified) + T-SPLIT. R14 was VALU-issue-bound in
// demand (~23 us) but ran at 44.5: total waves = m/32 = 4096 = only 4/SIMD,
// so the chain MFMA->16 dependent exp2->pack->serial O-accum was latency-
// exposed. The ONLY axis that creates waves is t: 2 blocks per (bh,msix),
// each sums half the t-range (no max-rescale -> partial sums add). Partial
// O (f32) + denominator go to per-half buffers; proj combines+normalizes.
// 8192 waves = 8/SIMD (VGPR ~56 <= 64, no LDS). Epilogue shuffles/divides
// deleted from attn.
__global__ __launch_bounds__(256) void attn_kernel(
        const unsigned short* __restrict__ qg,
        const unsigned short* __restrict__ vtg,
        float* __restrict__ mid32,       // [2][B*S][NE] partial O
        float* __restrict__ den) {       // [2][B*S][NH] partial denom
    const int bid = blockIdx.x;
    const int half = bid & 1;
    const int msix = (bid >> 1) & 15;
    const int bh = bid >> 5;
    const int b = bh >> 4, h = bh & (NH - 1);
    const int tid = threadIdx.x;

    const int wave = tid >> 6, lane = tid & 63;
    const int l31 = lane & 31, hi = lane >> 5;
    const int mb = msix * 128 + wave * 32;

    // B operand (q_m): col = l31, k = hi*8+j; hi=0 real (k=d 0..7), hi=1 zero.
    half8 hz = {0, 0, 0, 0, 0, 0, 0, 0};
    half8 bm = hi ? hz : *(const half8*)&qg[((size_t)bh * NS + mb + l31) * ND];

    const unsigned short* qt = qg + ((size_t)bh * NS + half * 1024 + l31) * ND;
    const int dv = (l31 < 9) ? l31 : 8;
    const unsigned short* vb = vtg + (size_t)bh * VT_BH + half * 64 * VT_BLK
                             + dv * 16 + hi * 8;

    f32x16 O = {0.f};
    const f32x16 zc = {0.f};

    for (int ch = 0; ch < 32; ch++) {
        // A (q_t rows tb..tb+31; lanes 32-63 broadcast rows, garbage k8-15
        // killed by B's zeroed k8-15)
        half8 at = *(const half8*)&qt[(size_t)ch * 32 * ND];
        half8 vf1 = *(const half8*)&vb[ch * 2 * VT_BLK];
        half8 vf2 = *(const half8*)&vb[ch * 2 * VT_BLK + VT_BLK];

        f32x16 s = __builtin_amdgcn_mfma_f32_32x32x16_f16(at, bm, zc, 0, 0, 0);

        half8 pA1 = mk_half8(
            pkrtz(__builtin_amdgcn_exp2f(s[0]),  __builtin_amdgcn_exp2f(s[1])),
            pkrtz(__builtin_amdgcn_exp2f(s[2]),  __builtin_amdgcn_exp2f(s[3])),
            pkrtz(__builtin_amdgcn_exp2f(s[4]),  __builtin_amdgcn_exp2f(s[5])),
            pkrtz(__builtin_amdgcn_exp2f(s[6]),  __builtin_amdgcn_exp2f(s[7])));
        half8 pA2 = mk_half8(
            pkrtz(__builtin_amdgcn_exp2f(s[8]),  __builtin_amdgcn_exp2f(s[9])),
            pkrtz(__builtin_amdgcn_exp2f(s[10]), __builtin_amdgcn_exp2f(s[11])),
            pkrtz(__builtin_amdgcn_exp2f(s[12]), __builtin_amdgcn_exp2f(s[13])),
            pkrtz(__builtin_amdgcn_exp2f(s[14]), __builtin_amdgcn_exp2f(s[15])));

        O = __builtin_amdgcn_mfma_f32_32x32x16_f16(pA1, vf1, O, 0, 0, 0);
        O = __builtin_amdgcn_mfma_f32_32x32x16_f16(pA2, vf2, O, 0, 0, 0);
    }

    // ---- epilogue: raw f32 partials; col 8 = denominator ----
    float* mp = mid32 + (size_t)half * NB * NS * NE;
    float* dp = den + (size_t)half * NB * NS * NH;
#pragma unroll
    for (int r = 0; r < 16; r++) {
        int m = mb + (r & 3) + 8 * (r >> 2) + 4 * hi;
        if (l31 < ND)
            mp[(size_t)(b * NS + m) * NE + h * ND + l31] = O[r];
        else if (l31 == ND)
            dp[(size_t)(b * NS + m) * NH + h] = O[r];
    }
}

// R15 proj: combine the two t-half partials, normalize, f16 MFMA with wf16.
// af = pkrtz((pa+pb) * rcp(da+db)); den index h = kt*4+quad (one per frag).
__global__ __launch_bounds__(512) void proj_kernel(
        const float* __restrict__ mid32,
        const float* __restrict__ den,
        const unsigned short* __restrict__ wf16,
        float* __restrict__ out) {
    const int rb = blockIdx.x * 16;
    const int tid = threadIdx.x;
    const int wavei = tid >> 6, lane = tid & 63;
    const int quad = lane >> 4, l15 = lane & 15;
    const int n0 = wavei * 16;

    const size_t row = (size_t)(rb + l15);
    const float* pa = mid32 + row * NE;
    const float* pb = pa + (size_t)NB * NS * NE;
    const float* da = den + row * NH;
    const float* db = da + (size_t)NB * NS * NH;

    f32x4 acc = {0.f, 0.f, 0.f, 0.f};
#pragma unroll
    for (int kt = 0; kt < 4; kt++) {
        const int k0 = kt * 32 + quad * 8;
        float4 a0 = *(const float4*)(pa + k0), a1 = *(const float4*)(pa + k0 + 4);
        float4 b0 = *(const float4*)(pb + k0), b1 = *(const float4*)(pb + k0 + 4);
        float rd = __builtin_amdgcn_rcpf(da[kt * 4 + quad] + db[kt * 4 + quad]);
        half8 af = mk_half8(
            pkrtz((a0.x + b0.x) * rd, (a0.y + b0.y) * rd),
            pkrtz((a0.z + b0.z) * rd, (a0.w + b0.w) * rd),
            pkrtz((a1.x + b1.x) * rd, (a1.y + b1.y) * rd),
            pkrtz((a1.z + b1.z) * rd, (a1.w + b1.w) * rd));
        half8 bf = *(const half8*)&wf16[(n0 + l15) * NE + k0];
        acc = __builtin_amdgcn_mfma_f32_16x16x32_f16(af, bf, acc, 0, 0, 0);
    }
#pragma unroll
    for (int r = 0; r < 4; r++)
        out[(size_t)(rb + quad * 4 + r) * NE + n0 + l15] = acc[r];
}

extern "C" void kernel_launch(void* const* d_in, const int* in_sizes, int n_in,
                              void* d_out, int out_size, void* d_ws, size_t ws_size,
                              hipStream_t stream) {
    const float* x     = (const float*)d_in[0];
    const float* theta = (const float*)d_in[1];
    const float* w_out = (const float*)d_in[2];
    const int*   mask  = (const int*)d_in[3];
    float* out = (float*)d_out;

    // workspace: mid32 2x4MB | den 2x512KB | qg 2MB | vtg 2.36MB | wf16 32KB
    float* mid32 = (float*)d_ws;
    float* den   = mid32 + (size_t)2 * NB * NS * NE;
    unsigned short* qg   = (unsigned short*)(den + (size_t)2 * NB * NS * NH);
    unsigned short* vtg  = qg + (size_t)NB * NH * NS * ND;
    unsigned short* wf16 = vtg + (size_t)NB * NH * VT_BH;

    qgen_kernel<<<NB * NH * NS / 2 / 256, 256, 0, stream>>>(x, theta, mask, w_out,
                                                            qg, vtg, wf16);
    attn_kernel<<<NB * NH * 16 * 2, 256, 0, stream>>>(qg, vtg, mid32, den);
    proj_kernel<<<NB * NS / 16, 512, 0, stream>>>(mid32, den, wf16, out);
}